// Round 2
// baseline (137.302 us; speedup 1.0000x reference)
//
#include <hip/hip_runtime.h>
#include <math.h>

#define W_    128
#define H_    128
#define HW    16384      // 128*128
#define D_    32
#define C_IN  8
#define K2    9
#define OC    16
#define CI    72         // C_IN*K2
#define NRED  524288.0f  // D_*HW per channel

// ws layout (bytes):
//   [0,128)      float sum[16], sumsq[16]
//   [256,14080)  wt transposed: wt[(ci*3+kd)*16 + o]
//   [16384, +16.78MB) x_t[(ry*128+rx)*8 + c][z]   (only if ws_size allows)

__global__ __launch_bounds__(256) void k_init(const float* __restrict__ wsrc,
                                              float* __restrict__ ws) {
    int t = threadIdx.x;
    if (t < 32) ws[t] = 0.f;
    for (int i = t; i < OC * CI * 3; i += 256) {
        int o   = i / (CI * 3);
        int rem = i - o * (CI * 3);
        int ci  = rem / 3;
        int kd  = rem - ci * 3;
        ws[64 + (ci * 3 + kd) * 16 + o] = wsrc[i];
    }
}

__global__ __launch_bounds__(256) void k_transpose(const float* __restrict__ x,
                                                   float* __restrict__ xt) {
    __shared__ float tile[32 * 132];
    int bid = blockIdx.x;
    int c  = bid >> 7;
    int ry = bid & 127;
    int t  = threadIdx.x;
    const float* src = x + c * (D_ * HW) + ry * W_;
    for (int k = 0; k < 4; ++k) {
        int e  = t * 4 + k * 1024;
        int z  = e >> 7;
        int rx = e & 127;
        float4 v = *reinterpret_cast<const float4*>(src + z * HW + rx);
        *reinterpret_cast<float4*>(&tile[z * 132 + rx]) = v;
    }
    __syncthreads();
    int rx = t >> 1;
    int zh = (t & 1) * 16;
    float* dst = xt + ((ry * W_ + rx) * C_IN + c) * D_ + zh;
    for (int i = 0; i < 4; ++i) {
        float4 v;
        v.x = tile[(zh + i * 4 + 0) * 132 + rx];
        v.y = tile[(zh + i * 4 + 1) * 132 + rx];
        v.z = tile[(zh + i * 4 + 2) * 132 + rx];
        v.w = tile[(zh + i * 4 + 3) * 132 + rx];
        *reinterpret_cast<float4*>(dst + i * 4) = v;
    }
}

template <bool XT>
__global__ __launch_bounds__(512) void k_main(const float* __restrict__ x,
                                              const float* __restrict__ xt,
                                              const float* __restrict__ dp,
                                              const float* __restrict__ nrm,
                                              const float* __restrict__ intri,
                                              const float* __restrict__ wt,
                                              float* __restrict__ out,
                                              float* __restrict__ stats) {
    __shared__ float s_cost[16 * 306];   // [p][dd=34][j=9], row stride 306
    __shared__ float s_z[4608];          // [(p*9+j)*32 + d]
    __shared__ float s_wgt[144], s_dp0[144], s_inv[144];
    __shared__ int   s_nb[144];
    __shared__ float s_dpc[512];         // [p][32]
    __shared__ float s_red[8 * 32];

    int t   = threadIdx.x;
    int bid = blockIdx.x;
    int r   = bid >> 3;            // 0..127
    int rx0 = (bid & 7) * 16;

    if (t < 144) {
        int p = t / 9, j = t - p * 9;
        int jd = j / 3;
        int dy = jd - 1, dx = (j - jd * 3) - 1;
        int cpix = rx0 + p;
        int ry  = min(max(r + dy, 0), H_ - 1);
        int rxn = min(max(cpix + dx, 0), W_ - 1);
        int nb  = ry * W_ + rxn;
        float fx = intri[0], cx = intri[2], fy = intri[4], cy = intri[5];
        float nx = nrm[nb], ny = nrm[HW + nb], nz = nrm[2 * HW + nb];
        float pu  = ((float)rxn  - cx) / fx;
        float pv  = ((float)ry   - cy) / fy;
        float puc = ((float)cpix - cx) / fx;
        float pvc = ((float)r    - cy) / fy;
        float num = nx * puc + ny * pvc + nz;
        float den = nx * pu + ny * pv + nz;
        if (fabsf(den) < 1e-8f)
            den = (den > 0.f) ? 1e-8f : ((den < 0.f) ? -1e-8f : 0.f);
        float w = num / den;
        if (!isfinite(w)) w = 1.0f;
        float d0  = dp[nb];
        float itv = dp[HW + nb] - d0;
        s_wgt[t] = w;
        s_dp0[t] = d0;
        s_inv[t] = 1.0f / itv;
        s_nb[t]  = nb;
    }
    {
        int p = t >> 5, d = t & 31;
        s_dpc[t] = dp[d * HW + r * W_ + rx0 + p];
    }
    if (t < 288) {  // zero pad rows dd=0 and dd=33
        int p = t / 18, rem = t - p * 18;
        int which = rem / 9, j = rem - which * 9;
        s_cost[p * 306 + which * (33 * 9) + j] = 0.f;
    }
    __syncthreads();

    for (int fid = t; fid < 4608; fid += 512) {
        int d  = fid & 31;
        int pj = fid >> 5;
        int p  = pj / 9;
        s_z[fid] = (s_wgt[pj] * s_dpc[p * 32 + d] - s_dp0[pj]) * s_inv[pj];
    }
    __syncthreads();

    float acc[16];
#pragma unroll
    for (int o = 0; o < 16; ++o) acc[o] = 0.f;

    int pc = t & 15;   // conv: pixel
    int dc = t >> 4;   // conv: depth

    for (int c = 0; c < C_IN; ++c) {
        // ---- fill cost slice for channel c ----
        for (int fid = t; fid < 4608; fid += 512) {
            int d  = fid & 31;
            int pj = fid >> 5;
            float z = s_z[fid];
            float val = 0.f;
            if (fabsf(z) < 1e6f) {
                float z0f = floorf(z);
                float fz  = z - z0f;
                int z0    = (int)z0f;
                int nb    = s_nb[pj];
                float v0 = 0.f, v1 = 0.f;
                if (XT) {
                    const float* col = xt + nb * (C_IN * D_) + c * D_;
                    if (z0 >= 0 && z0 < D_)      v0 = col[z0];
                    if (z0 >= -1 && z0 < D_ - 1) v1 = col[z0 + 1];
                } else {
                    const float* pl = x + c * (D_ * HW) + nb;
                    if (z0 >= 0 && z0 < D_)      v0 = pl[z0 * HW];
                    if (z0 >= -1 && z0 < D_ - 1) v1 = pl[(z0 + 1) * HW];
                }
                val = (1.f - fz) * v0 + fz * v1;
            }
            int p = pj / 9, j = pj - p * 9;
            s_cost[p * 306 + (d + 1) * 9 + j] = val;
        }
        __syncthreads();

        // ---- partial conv for channel c ----
        const float* wc   = wt + c * (K2 * 3 * 16);
        const float* crow = s_cost + pc * 306;
#pragma unroll
        for (int j = 0; j < 9; ++j) {
#pragma unroll
            for (int kd = 0; kd < 3; ++kd) {
                float v = crow[(dc + kd) * 9 + j];
                const float4* w4 = reinterpret_cast<const float4*>(wc + (j * 3 + kd) * 16);
                float4 a = w4[0], b = w4[1], c2 = w4[2], d2 = w4[3];
                acc[0]  += v * a.x;  acc[1]  += v * a.y;
                acc[2]  += v * a.z;  acc[3]  += v * a.w;
                acc[4]  += v * b.x;  acc[5]  += v * b.y;
                acc[6]  += v * b.z;  acc[7]  += v * b.w;
                acc[8]  += v * c2.x; acc[9]  += v * c2.y;
                acc[10] += v * c2.z; acc[11] += v * c2.w;
                acc[12] += v * d2.x; acc[13] += v * d2.y;
                acc[14] += v * d2.z; acc[15] += v * d2.w;
            }
        }
        __syncthreads();
    }

    // ---- store y (4 full cache lines per wave-store) ----
    float* obase = out + r * W_ + rx0 + pc;
#pragma unroll
    for (int o = 0; o < 16; ++o) obase[(o * D_ + dc) * HW] = acc[o];

    // ---- BN stats: wave reduce -> LDS -> 32 atomics/block ----
#pragma unroll
    for (int o = 0; o < 16; ++o) {
        float v = acc[o], sq = v * v;
#pragma unroll
        for (int m = 1; m < 64; m <<= 1) {
            v  += __shfl_xor(v, m, 64);
            sq += __shfl_xor(sq, m, 64);
        }
        if ((t & 63) == 0) {
            int wv = t >> 6;
            s_red[wv * 32 + o]      = v;
            s_red[wv * 32 + 16 + o] = sq;
        }
    }
    __syncthreads();
    if (t < 32) {
        float s = 0.f;
        for (int wv = 0; wv < 8; ++wv) s += s_red[wv * 32 + t];
        atomicAdd(&stats[t], s);
    }
}

__global__ __launch_bounds__(256) void k_bn(float* __restrict__ out,
                                            const float* __restrict__ stats,
                                            const float* __restrict__ gamma,
                                            const float* __restrict__ beta) {
    int i4 = blockIdx.x * 256 + threadIdx.x;   // 2,097,152 float4s
    int o  = i4 >> 17;
    float invN = 1.f / NRED;
    float mean = stats[o] * invN;
    float var  = stats[16 + o] * invN - mean * mean;
    float rstd = rsqrtf(var + 1e-5f);
    float a = gamma[o] * rstd;
    float b = beta[o] - mean * a;
    float4 y = reinterpret_cast<float4*>(out)[i4];
    y.x = fmaxf(0.f, fmaf(y.x, a, b));
    y.y = fmaxf(0.f, fmaf(y.y, a, b));
    y.z = fmaxf(0.f, fmaf(y.z, a, b));
    y.w = fmaxf(0.f, fmaf(y.w, a, b));
    reinterpret_cast<float4*>(out)[i4] = y;
}

extern "C" void kernel_launch(void* const* d_in, const int* in_sizes, int n_in,
                              void* d_out, int out_size, void* d_ws, size_t ws_size,
                              hipStream_t stream) {
    const float* x     = (const float*)d_in[0];
    const float* dp    = (const float*)d_in[1];
    const float* nrm   = (const float*)d_in[2];
    const float* intri = (const float*)d_in[3];
    const float* wsrc  = (const float*)d_in[4];
    const float* gamma = (const float*)d_in[5];
    const float* beta  = (const float*)d_in[6];
    float* out = (float*)d_out;
    float* ws  = (float*)d_ws;

    bool xt_ok = ws_size >= (size_t)(16384 + 4194304 * 4);
    float* xt = ws + 4096;

    hipLaunchKernelGGL(k_init, dim3(1), dim3(256), 0, stream, wsrc, ws);
    if (xt_ok) {
        hipLaunchKernelGGL(k_transpose, dim3(1024), dim3(256), 0, stream, x, xt);
        hipLaunchKernelGGL(k_main<true>, dim3(1024), dim3(512), 0, stream,
                           x, xt, dp, nrm, intri, ws + 64, out, ws);
    } else {
        hipLaunchKernelGGL(k_main<false>, dim3(1024), dim3(512), 0, stream,
                           x, xt, dp, nrm, intri, ws + 64, out, ws);
    }
    hipLaunchKernelGGL(k_bn, dim3(8192), dim3(256), 0, stream, out, ws, gamma, beta);
}

// Round 4
// 104.737 us; speedup vs baseline: 1.3109x; 1.3109x over previous
//
#include <hip/hip_runtime.h>
#include <math.h>

#define W_    128
#define H_    128
#define HW    16384      // 128*128
#define D_    32
#define C_IN  8
#define K2    9
#define OC    16
#define CI    72         // C_IN*K2
#define NRED  524288.0f  // D_*HW per channel

// ws layout (floats):
//   [0,32)      sum[16], sumsq[16]
//   [64,3520)   wt transposed: wt[(ci*3+kd)*16 + o]
//   [4096, +4194304) x_t[c][ry*128+rx][z]   (only if ws_size allows)

__global__ __launch_bounds__(256) void k_init(const float* __restrict__ wsrc,
                                              float* __restrict__ ws) {
    int t = threadIdx.x;
    if (t < 32) ws[t] = 0.f;
    for (int i = t; i < OC * CI * 3; i += 256) {
        int o   = i / (CI * 3);
        int rem = i - o * (CI * 3);
        int ci  = rem / 3;
        int kd  = rem - ci * 3;
        ws[64 + (ci * 3 + kd) * 16 + o] = wsrc[i];
    }
}

// x[c][z][ry][rx] -> xt[c][ry*128+rx][z]
__global__ __launch_bounds__(256) void k_transpose(const float* __restrict__ x,
                                                   float* __restrict__ xt) {
    __shared__ float tile[32 * 132];
    int bid = blockIdx.x;
    int c  = bid >> 7;
    int ry = bid & 127;
    int t  = threadIdx.x;
    const float* src = x + c * (D_ * HW) + ry * W_;
    for (int k = 0; k < 4; ++k) {
        int e  = t * 4 + k * 1024;
        int z  = e >> 7;
        int rx = e & 127;
        float4 v = *reinterpret_cast<const float4*>(src + z * HW + rx);
        *reinterpret_cast<float4*>(&tile[z * 132 + rx]) = v;
    }
    __syncthreads();
    int rx = t >> 1;
    int zh = (t & 1) * 16;
    float* dst = xt + ((size_t)(c * HW + ry * W_ + rx)) * D_ + zh;
    for (int i = 0; i < 4; ++i) {
        float4 v;
        v.x = tile[(zh + i * 4 + 0) * 132 + rx];
        v.y = tile[(zh + i * 4 + 1) * 132 + rx];
        v.z = tile[(zh + i * 4 + 2) * 132 + rx];
        v.w = tile[(zh + i * 4 + 3) * 132 + rx];
        *reinterpret_cast<float4*>(dst + i * 4) = v;
    }
}

template <bool XT>
__global__ __launch_bounds__(512, 6) void k_main(const float* __restrict__ x,
                                                 const float* __restrict__ xt,
                                                 const float* __restrict__ dp,
                                                 const float* __restrict__ nrm,
                                                 const float* __restrict__ intri,
                                                 const float* __restrict__ wt,
                                                 float* __restrict__ out,
                                                 float* __restrict__ stats) {
    __shared__ float s_cost[16 * 306];   // [p][dd=34][j=9]
    __shared__ float s_x[2][1728];       // [seg3][18px][32z], double-buffered
    __shared__ float s_wgt[144], s_dp0[144], s_inv[144];
    __shared__ float s_dpc[512];         // [p][32]
    __shared__ float s_red[8 * 32];

    int t   = threadIdx.x;
    int bid = blockIdx.x;
    int r   = bid >> 3;            // 0..127
    int rx0 = (bid & 7) * 16;

    // ---- staging geometry (t < 432): seg 0..2, px 0..17, zq = float4 quarter ----
    int seg = t / 144;
    int f   = t - seg * 144;
    int spx = f >> 3;
    int zq  = f & 7;
    int srow = min(max(r + seg - 1, 0), H_ - 1);
    int scol = min(max(rx0 - 1 + spx, 0), W_ - 1);
    const float* gsrc = xt + ((size_t)(srow * W_ + scol)) * D_ + zq * 4;
    const float* gsrc_raw = x + (srow * W_ + scol) + (size_t)(zq * 4) * HW;

    float4 sv;
    if (t < 432) {
        if (XT) {
            sv = *reinterpret_cast<const float4*>(gsrc);
        } else {
            sv.x = gsrc_raw[0];
            sv.y = gsrc_raw[HW];
            sv.z = gsrc_raw[2 * HW];
            sv.w = gsrc_raw[3 * HW];
        }
    }

    if (t < 144) {
        int p = t / 9, j = t - p * 9;
        int jd = j / 3;
        int dy = jd - 1, dx = (j - jd * 3) - 1;
        int cpix = rx0 + p;
        int ry  = min(max(r + dy, 0), H_ - 1);
        int rxn = min(max(cpix + dx, 0), W_ - 1);
        int nb  = ry * W_ + rxn;
        float fx = intri[0], cx = intri[2], fy = intri[4], cy = intri[5];
        float nx = nrm[nb], ny = nrm[HW + nb], nz = nrm[2 * HW + nb];
        float pu  = ((float)rxn  - cx) / fx;
        float pv  = ((float)ry   - cy) / fy;
        float puc = ((float)cpix - cx) / fx;
        float pvc = ((float)r    - cy) / fy;
        float num = nx * puc + ny * pvc + nz;
        float den = nx * pu + ny * pv + nz;
        if (fabsf(den) < 1e-8f)
            den = (den > 0.f) ? 1e-8f : ((den < 0.f) ? -1e-8f : 0.f);
        float w = num / den;
        if (!isfinite(w)) w = 1.0f;
        float d0  = dp[nb];
        float itv = dp[HW + nb] - d0;
        s_wgt[t] = w;
        s_dp0[t] = d0;
        s_inv[t] = 1.0f / itv;
    }
    s_dpc[t] = dp[(t & 31) * HW + r * W_ + rx0 + (t >> 5)];
    if (t < 288) {  // zero pad rows dd=0 and dd=33 (written once, never overwritten)
        int p = t / 18, rem = t - p * 18;
        int which = rem / 9, j = rem - which * 9;
        s_cost[p * 306 + which * (33 * 9) + j] = 0.f;
    }
    if (t < 432) *reinterpret_cast<float4*>(&s_x[0][t * 4]) = sv;
    __syncthreads();

    // ---- per-thread gather descriptors (9 fids, cached in registers) ----
    // desc: bits[0:11]=off0, bit[11]=off1-off0, bits[12:25]=dst index in s_cost
    int dcol = t & 31;
    int pjb  = t >> 5;
    int base9 = (dcol + 1) * 9;
    unsigned dsc[9];
    float fw0[9], fw1[9];
#pragma unroll
    for (int i = 0; i < 9; ++i) {
        int pj = pjb + 16 * i;
        int p  = pj / 9;
        int j  = pj - p * 9;
        int jd = j / 3;
        int jx = j - jd * 3;
        float z   = (s_wgt[pj] * s_dpc[p * 32 + dcol] - s_dp0[pj]) * s_inv[pj];
        float zc  = fminf(fmaxf(z, -2.0f), 34.0f);   // NaN -> -2 (weights zero)
        float z0f = floorf(zc);
        float fz  = zc - z0f;
        int   z0  = (int)z0f;
        fw0[i] = (z0 >= 0  && z0 < 32) ? 1.0f - fz : 0.0f;
        fw1[i] = (z0 >= -1 && z0 < 31) ? fz : 0.0f;
        int cb = (jd * 18 + p + jx) * 32;
        int o0 = cb + min(max(z0, 0), 31);
        unsigned delta = (z0 >= 0 && z0 < 31) ? 1u : 0u;
        unsigned dst = (unsigned)(p * 306 + base9 + j);
        dsc[i] = (unsigned)o0 | (delta << 11) | (dst << 12);
    }

    float acc[16];
#pragma unroll
    for (int o = 0; o < 16; ++o) acc[o] = 0.f;

    int pc = t & 15;   // conv: pixel
    int dc = t >> 4;   // conv: depth
    const float* crow = s_cost + pc * 306;

    for (int c = 0; c < C_IN; ++c) {
        // issue next channel's stage loads (latency hides under fill)
        if (c < 7 && t < 432) {
            if (XT) {
                sv = *reinterpret_cast<const float4*>(gsrc + (size_t)(c + 1) * (HW * D_));
            } else {
                const float* b = gsrc_raw + (size_t)(c + 1) * (D_ * HW);
                sv.x = b[0]; sv.y = b[HW]; sv.z = b[2 * HW]; sv.w = b[3 * HW];
            }
        }
        // ---- fill cost slice for channel c from staged LDS ----
        const float* sx = s_x[c & 1];
#pragma unroll
        for (int i = 0; i < 9; ++i) {
            unsigned v  = dsc[i];
            unsigned o0 = v & 0x7ffu;
            unsigned o1 = o0 + ((v >> 11) & 1u);
            float val = fw0[i] * sx[o0] + fw1[i] * sx[o1];
            s_cost[v >> 12] = val;
        }
        if (c < 7 && t < 432) *reinterpret_cast<float4*>(&s_x[(c + 1) & 1][t * 4]) = sv;
        __syncthreads();

        // ---- partial conv for channel c ----
        const float* wc = wt + c * (K2 * 3 * 16);
#pragma unroll
        for (int j = 0; j < 9; ++j) {
#pragma unroll
            for (int kd = 0; kd < 3; ++kd) {
                float v = crow[(dc + kd) * 9 + j];
                const float4* w4 = reinterpret_cast<const float4*>(wc + (j * 3 + kd) * 16);
                float4 a = w4[0], b = w4[1], c2 = w4[2], d2 = w4[3];
                acc[0]  += v * a.x;  acc[1]  += v * a.y;
                acc[2]  += v * a.z;  acc[3]  += v * a.w;
                acc[4]  += v * b.x;  acc[5]  += v * b.y;
                acc[6]  += v * b.z;  acc[7]  += v * b.w;
                acc[8]  += v * c2.x; acc[9]  += v * c2.y;
                acc[10] += v * c2.z; acc[11] += v * c2.w;
                acc[12] += v * d2.x; acc[13] += v * d2.y;
                acc[14] += v * d2.z; acc[15] += v * d2.w;
            }
        }
        __syncthreads();
    }

    // ---- store y (full-line coalesced) ----
    float* obase = out + r * W_ + rx0 + pc;
#pragma unroll
    for (int o = 0; o < 16; ++o) obase[(o * D_ + dc) * HW] = acc[o];

    // ---- BN stats: wave reduce -> LDS -> 32 atomics/block ----
#pragma unroll
    for (int o = 0; o < 16; ++o) {
        float v = acc[o], sq = v * v;
#pragma unroll
        for (int m = 1; m < 64; m <<= 1) {
            v  += __shfl_xor(v, m, 64);
            sq += __shfl_xor(sq, m, 64);
        }
        if ((t & 63) == 0) {
            int wv = t >> 6;
            s_red[wv * 32 + o]      = v;
            s_red[wv * 32 + 16 + o] = sq;
        }
    }
    __syncthreads();
    if (t < 32) {
        float s = 0.f;
        for (int wv = 0; wv < 8; ++wv) s += s_red[wv * 32 + t];
        atomicAdd(&stats[t], s);
    }
}

__global__ __launch_bounds__(256) void k_bn(float* __restrict__ out,
                                            const float* __restrict__ stats,
                                            const float* __restrict__ gamma,
                                            const float* __restrict__ beta) {
    int i4 = blockIdx.x * 256 + threadIdx.x;   // 2,097,152 float4s
    int o  = i4 >> 17;
    float invN = 1.f / NRED;
    float mean = stats[o] * invN;
    float var  = stats[16 + o] * invN - mean * mean;
    float rstd = rsqrtf(var + 1e-5f);
    float a = gamma[o] * rstd;
    float b = beta[o] - mean * a;
    float4 y = reinterpret_cast<float4*>(out)[i4];
    y.x = fmaxf(0.f, fmaf(y.x, a, b));
    y.y = fmaxf(0.f, fmaf(y.y, a, b));
    y.z = fmaxf(0.f, fmaf(y.z, a, b));
    y.w = fmaxf(0.f, fmaf(y.w, a, b));
    reinterpret_cast<float4*>(out)[i4] = y;
}

extern "C" void kernel_launch(void* const* d_in, const int* in_sizes, int n_in,
                              void* d_out, int out_size, void* d_ws, size_t ws_size,
                              hipStream_t stream) {
    const float* x     = (const float*)d_in[0];
    const float* dp    = (const float*)d_in[1];
    const float* nrm   = (const float*)d_in[2];
    const float* intri = (const float*)d_in[3];
    const float* wsrc  = (const float*)d_in[4];
    const float* gamma = (const float*)d_in[5];
    const float* beta  = (const float*)d_in[6];
    float* out = (float*)d_out;
    float* ws  = (float*)d_ws;

    bool xt_ok = ws_size >= (size_t)(16384 + 4194304 * 4);
    float* xt = ws + 4096;

    hipLaunchKernelGGL(k_init, dim3(1), dim3(256), 0, stream, wsrc, ws);
    if (xt_ok) {
        hipLaunchKernelGGL(k_transpose, dim3(1024), dim3(256), 0, stream, x, xt);
        hipLaunchKernelGGL(k_main<true>, dim3(1024), dim3(512), 0, stream,
                           x, xt, dp, nrm, intri, ws + 64, out, ws);
    } else {
        hipLaunchKernelGGL(k_main<false>, dim3(1024), dim3(512), 0, stream,
                           x, xt, dp, nrm, intri, ws + 64, out, ws);
    }
    hipLaunchKernelGGL(k_bn, dim3(8192), dim3(256), 0, stream, out, ws, gamma, beta);
}